// Round 1
// baseline (160.402 us; speedup 1.0000x reference)
//
#include <hip/hip_runtime.h>
#include <hip/hip_bf16.h>

// MatmulAttention: x = [2,16,2048,64] f32, q=k=v=x, no 1/sqrt(d) scale.
// out = softmax(q k^T) v, f32.
// Flash-style fused kernel, bf16 MFMA (16x16x32), fp32 online softmax.

typedef __bf16 bf16x8 __attribute__((ext_vector_type(8)));
typedef float f32x4 __attribute__((ext_vector_type(4)));

#define SEQ 2048
#define HD 64
#define KVB 64
#define NWAVE 4
#define QPW 32   // q rows per wave
#define QPB 128  // q rows per block
#define NBH 32   // batch*heads

// XOR swizzle: spreads 128B-stride rows across banks for 16B LDS accesses.
__device__ __forceinline__ int swz(int row, int byteoff) {
    return byteoff ^ ((row & 7) << 4);
}

__global__ __launch_bounds__(256, 2)
void attn_fwd_kernel(const float* __restrict__ x, float* __restrict__ out) {
    __shared__ __align__(16) char k_lds[KVB * HD * 2];             // [kv][d] bf16, swizzled
    __shared__ __align__(16) char vt_lds[HD * KVB * 2];            // [d][kv] bf16, swizzled
    __shared__ __align__(16) char p_lds[NWAVE][2][16 * KVB * 2];   // per wave/rowtile [16][64] bf16

    const int bh = blockIdx.y;
    const int q0 = blockIdx.x * QPB;
    const float* __restrict__ X = x + (size_t)bh * SEQ * HD;
    float* __restrict__ Op = out + (size_t)bh * SEQ * HD;

    const int t = threadIdx.x;
    const int wave = t >> 6;
    const int lane = t & 63;
    const int lgrp = lane >> 4;   // 0..3
    const int lid  = lane & 15;   // 0..15

    // ---- hoist Q fragments (A-layout: row=lane&15, k=(lane>>4)*8+b) ----
    bf16x8 qf[2][2];
#pragma unroll
    for (int rt = 0; rt < 2; ++rt) {
        const int row = q0 + wave * QPW + rt * 16 + lid;
#pragma unroll
        for (int kc = 0; kc < 2; ++kc) {
            const float* src = X + (size_t)row * HD + kc * 32 + lgrp * 8;
            float4 a = *(const float4*)src;
            float4 b = *(const float4*)(src + 4);
            bf16x8 f;
            f[0] = (__bf16)a.x; f[1] = (__bf16)a.y; f[2] = (__bf16)a.z; f[3] = (__bf16)a.w;
            f[4] = (__bf16)b.x; f[5] = (__bf16)b.y; f[6] = (__bf16)b.z; f[7] = (__bf16)b.w;
            qf[rt][kc] = f;
        }
    }

    f32x4 acc[2][4];
    float m[2][4], l[2][4];
#pragma unroll
    for (int rt = 0; rt < 2; ++rt)
#pragma unroll
        for (int i = 0; i < 4; ++i) {
            acc[rt][i][0] = 0.f; acc[rt][i][1] = 0.f;
            acc[rt][i][2] = 0.f; acc[rt][i][3] = 0.f;
            m[rt][i] = -1e30f;
            l[rt][i] = 0.f;
        }

    const int srow = t >> 2;        // 0..63 (staging row)
    const int scq  = (t & 3) * 16;  // 0,16,32,48 (staging col quarter)

    for (int kv0 = 0; kv0 < SEQ; kv0 += KVB) {
        // ---- stage K tile [64 kv][64 d] as bf16 (swizzled) ----
        {
            const float* src = X + (size_t)(kv0 + srow) * HD + scq;
            float4 a = *(const float4*)(src);
            float4 b = *(const float4*)(src + 4);
            float4 c = *(const float4*)(src + 8);
            float4 d = *(const float4*)(src + 12);
            bf16x8 f0, f1;
            f0[0] = (__bf16)a.x; f0[1] = (__bf16)a.y; f0[2] = (__bf16)a.z; f0[3] = (__bf16)a.w;
            f0[4] = (__bf16)b.x; f0[5] = (__bf16)b.y; f0[6] = (__bf16)b.z; f0[7] = (__bf16)b.w;
            f1[0] = (__bf16)c.x; f1[1] = (__bf16)c.y; f1[2] = (__bf16)c.z; f1[3] = (__bf16)c.w;
            f1[4] = (__bf16)d.x; f1[5] = (__bf16)d.y; f1[6] = (__bf16)d.z; f1[7] = (__bf16)d.w;
            *(bf16x8*)&k_lds[swz(srow, srow * 128 + scq * 2)]      = f0;
            *(bf16x8*)&k_lds[swz(srow, srow * 128 + scq * 2 + 16)] = f1;
        }
        // ---- stage V^T tile [64 d][64 kv] as bf16 (swizzled) ----
        {
            bf16x8 g0, g1;
#pragma unroll
            for (int j = 0; j < 8; ++j)
                g0[j] = (__bf16)X[(size_t)(kv0 + scq + j) * HD + srow];
#pragma unroll
            for (int j = 0; j < 8; ++j)
                g1[j] = (__bf16)X[(size_t)(kv0 + scq + 8 + j) * HD + srow];
            *(bf16x8*)&vt_lds[swz(srow, srow * 128 + scq * 2)]      = g0;
            *(bf16x8*)&vt_lds[swz(srow, srow * 128 + scq * 2 + 16)] = g1;
        }
        __syncthreads();

#pragma unroll
        for (int rt = 0; rt < 2; ++rt) {
            // ---- S = Q K^T for this 16-row tile: 4 key-subtiles ----
            f32x4 s[4];
#pragma unroll
            for (int kt = 0; kt < 4; ++kt) {
                f32x4 z = {0.f, 0.f, 0.f, 0.f};
#pragma unroll
                for (int kc = 0; kc < 2; ++kc) {
                    const int krow = kt * 16 + lid;
                    bf16x8 kf = *(const bf16x8*)&k_lds[swz(krow, krow * 128 + (kc * 32 + lgrp * 8) * 2)];
                    z = __builtin_amdgcn_mfma_f32_16x16x32_bf16(qf[rt][kc], kf, z, 0, 0, 0);
                }
                s[kt] = z;
            }

            // ---- online softmax (D-layout: row = lgrp*4 + r, col = kt*16+lid) ----
            char* pl = p_lds[wave][rt];
#pragma unroll
            for (int r = 0; r < 4; ++r) {
                float mx = fmaxf(fmaxf(s[0][r], s[1][r]), fmaxf(s[2][r], s[3][r]));
                mx = fmaxf(mx, __shfl_xor(mx, 1));
                mx = fmaxf(mx, __shfl_xor(mx, 2));
                mx = fmaxf(mx, __shfl_xor(mx, 4));
                mx = fmaxf(mx, __shfl_xor(mx, 8));
                const float mold = m[rt][r];
                const float mnew = fmaxf(mold, mx);
                const float alpha = __expf(mold - mnew);
                const int prow = lgrp * 4 + r;
                float psum = 0.f;
#pragma unroll
                for (int kt = 0; kt < 4; ++kt) {
                    float p = __expf(s[kt][r] - mnew);
                    psum += p;
                    *(__bf16*)&pl[swz(prow, prow * 128 + (kt * 16 + lid) * 2)] = (__bf16)p;
                }
                psum += __shfl_xor(psum, 1);
                psum += __shfl_xor(psum, 2);
                psum += __shfl_xor(psum, 4);
                psum += __shfl_xor(psum, 8);
                l[rt][r] = l[rt][r] * alpha + psum;
                m[rt][r] = mnew;
#pragma unroll
                for (int ct = 0; ct < 4; ++ct)
                    acc[rt][ct][r] *= alpha;
            }

            // ---- O += P V ----
#pragma unroll
            for (int kc = 0; kc < 2; ++kc) {
                bf16x8 pf = *(const bf16x8*)&pl[swz(lid, lid * 128 + (kc * 32 + lgrp * 8) * 2)];
#pragma unroll
                for (int ct = 0; ct < 4; ++ct) {
                    const int vrow = ct * 16 + lid;
                    bf16x8 vf = *(const bf16x8*)&vt_lds[swz(vrow, vrow * 128 + (kc * 32 + lgrp * 8) * 2)];
                    acc[rt][ct] = __builtin_amdgcn_mfma_f32_16x16x32_bf16(pf, vf, acc[rt][ct], 0, 0, 0);
                }
            }
        }
        __syncthreads();
    }

    // ---- epilogue: normalize and store f32 ----
#pragma unroll
    for (int rt = 0; rt < 2; ++rt)
#pragma unroll
        for (int r = 0; r < 4; ++r) {
            const float inv = 1.f / l[rt][r];
            const int row = q0 + wave * QPW + rt * 16 + lgrp * 4 + r;
            float* dst = Op + (size_t)row * HD + lid;
#pragma unroll
            for (int ct = 0; ct < 4; ++ct)
                dst[ct * 16] = acc[rt][ct][r] * inv;
        }
}

extern "C" void kernel_launch(void* const* d_in, const int* in_sizes, int n_in,
                              void* d_out, int out_size, void* d_ws, size_t ws_size,
                              hipStream_t stream) {
    const float* x = (const float*)d_in[0];
    float* out = (float*)d_out;
    dim3 grid(SEQ / QPB, NBH);
    dim3 block(256);
    hipLaunchKernelGGL(attn_fwd_kernel, grid, block, 0, stream, x, out);
}

// Round 2
// 119.365 us; speedup vs baseline: 1.3438x; 1.3438x over previous
//
#include <hip/hip_runtime.h>
#include <hip/hip_bf16.h>
#include <stdint.h>

// MatmulAttention: x = [2,16,2048,64] f32, q=k=v=x, no 1/sqrt(d) scale.
// out = softmax(q k^T) v, f32.
// R2: prepass builds pre-swizzled bf16 K / V^T tile images in ws (shared by
// all q-blocks of a head); flash kernel double-buffers them through LDS with
// reg-staged async split (T14), QPW=32, exp2-domain softmax, setprio (T5).

typedef __bf16 bf16x8 __attribute__((ext_vector_type(8)));
typedef float f32x4 __attribute__((ext_vector_type(4)));

#define SEQ 2048
#define HD 64
#define KVB 64
#define NBH 32
#define NTILE (SEQ / KVB)        // 32 kv tiles
#define IMG_BYTES 8192           // one 64x64 bf16 tile image
#define PAIR_BYTES 16384         // K image + VT image
#define WS_NEEDED ((size_t)NBH * NTILE * PAIR_BYTES)  // 16 MB

#define QPB 128  // q rows per block
#define QPW 32   // q rows per wave (2 x 16-row MFMA tiles)

// XOR swizzle: spreads 128B-stride rows across banks for 16B LDS accesses.
__device__ __forceinline__ int swz(int row, int byteoff) {
    return byteoff ^ ((row & 7) << 4);
}

__device__ __forceinline__ float fexp2(float x) {
    float r;
    asm("v_exp_f32 %0, %1" : "=v"(r) : "v"(x));
    return r;
}

// ---------------- prepass: build bf16 tile images ----------------
__global__ __launch_bounds__(256)
void prep_kernel(const float* __restrict__ x, char* __restrict__ ws) {
    const int bh = blockIdx.y;
    const int tile = blockIdx.x;
    const int kv0 = tile * KVB;
    const int t = threadIdx.x;
    const int srow = t >> 2;        // 0..63
    const int scq = (t & 3) * 16;   // 0,16,32,48
    const float* __restrict__ X = x + (size_t)bh * SEQ * HD;
    char* __restrict__ img = ws + ((size_t)bh * NTILE + tile) * PAIR_BYTES;

    // K image: [kv][d] bf16, swizzled rows
    {
        const float* src = X + (size_t)(kv0 + srow) * HD + scq;
        float4 a = *(const float4*)(src);
        float4 b = *(const float4*)(src + 4);
        float4 c = *(const float4*)(src + 8);
        float4 d = *(const float4*)(src + 12);
        bf16x8 f0, f1;
        f0[0] = (__bf16)a.x; f0[1] = (__bf16)a.y; f0[2] = (__bf16)a.z; f0[3] = (__bf16)a.w;
        f0[4] = (__bf16)b.x; f0[5] = (__bf16)b.y; f0[6] = (__bf16)b.z; f0[7] = (__bf16)b.w;
        f1[0] = (__bf16)c.x; f1[1] = (__bf16)c.y; f1[2] = (__bf16)c.z; f1[3] = (__bf16)c.w;
        f1[4] = (__bf16)d.x; f1[5] = (__bf16)d.y; f1[6] = (__bf16)d.z; f1[7] = (__bf16)d.w;
        *(bf16x8*)&img[swz(srow, srow * 128 + scq * 2)] = f0;
        *(bf16x8*)&img[swz(srow, srow * 128 + scq * 2 + 16)] = f1;
    }
    // VT image: [d][kv] bf16, swizzled rows (row = d = srow, col = kv)
    {
        bf16x8 g0, g1;
#pragma unroll
        for (int j = 0; j < 8; ++j)
            g0[j] = (__bf16)X[(size_t)(kv0 + scq + j) * HD + srow];
#pragma unroll
        for (int j = 0; j < 8; ++j)
            g1[j] = (__bf16)X[(size_t)(kv0 + scq + 8 + j) * HD + srow];
        *(bf16x8*)&img[IMG_BYTES + swz(srow, srow * 128 + scq * 2)] = g0;
        *(bf16x8*)&img[IMG_BYTES + swz(srow, srow * 128 + scq * 2 + 16)] = g1;
    }
}

// ---------------- main fused attention (image-fed) ----------------
__global__ __launch_bounds__(256, 2)
void attn2_kernel(const float* __restrict__ x, const char* __restrict__ ws,
                  float* __restrict__ out) {
    __shared__ __align__(16) char kbuf[2][IMG_BYTES];
    __shared__ __align__(16) char vbuf[2][IMG_BYTES];
    __shared__ __align__(16) char p_lds[4][2][16 * KVB * 2];

    const int bh = blockIdx.y;
    const int q0 = blockIdx.x * QPB;
    const float* __restrict__ X = x + (size_t)bh * SEQ * HD;
    float* __restrict__ Op = out + (size_t)bh * SEQ * HD;
    const char* __restrict__ wsb = ws + (size_t)bh * NTILE * PAIR_BYTES;

    const int t = threadIdx.x;
    const int wave = t >> 6;
    const int lane = t & 63;
    const int lgrp = lane >> 4;
    const int lid = lane & 15;

    // ---- hoist Q fragments, pre-scaled by log2(e) (exp2-domain softmax) ----
    const float SCL = 1.4426950408889634f;
    bf16x8 qf[2][2];
#pragma unroll
    for (int rt = 0; rt < 2; ++rt) {
        const int row = q0 + wave * QPW + rt * 16 + lid;
#pragma unroll
        for (int kc = 0; kc < 2; ++kc) {
            const float* src = X + (size_t)row * HD + kc * 32 + lgrp * 8;
            float4 a = *(const float4*)src;
            float4 b = *(const float4*)(src + 4);
            bf16x8 f;
            f[0] = (__bf16)(a.x * SCL); f[1] = (__bf16)(a.y * SCL);
            f[2] = (__bf16)(a.z * SCL); f[3] = (__bf16)(a.w * SCL);
            f[4] = (__bf16)(b.x * SCL); f[5] = (__bf16)(b.y * SCL);
            f[6] = (__bf16)(b.z * SCL); f[7] = (__bf16)(b.w * SCL);
            qf[rt][kc] = f;
        }
    }

    f32x4 acc[2][4];
    float m[2][4], l[2][4];
#pragma unroll
    for (int rt = 0; rt < 2; ++rt)
#pragma unroll
        for (int i = 0; i < 4; ++i) {
            acc[rt][i][0] = 0.f; acc[rt][i][1] = 0.f;
            acc[rt][i][2] = 0.f; acc[rt][i][3] = 0.f;
            m[rt][i] = -1e30f;
            l[rt][i] = 0.f;
        }

    // ---- prologue: stage tile 0 ----
    {
        const char* img = wsb;
        bf16x8 d0 = *(const bf16x8*)(img + t * 16);
        bf16x8 d1 = *(const bf16x8*)(img + 4096 + t * 16);
        bf16x8 d2 = *(const bf16x8*)(img + 8192 + t * 16);
        bf16x8 d3 = *(const bf16x8*)(img + 12288 + t * 16);
        *(bf16x8*)&kbuf[0][t * 16] = d0;
        *(bf16x8*)&kbuf[0][4096 + t * 16] = d1;
        *(bf16x8*)&vbuf[0][t * 16] = d2;
        *(bf16x8*)&vbuf[0][4096 + t * 16] = d3;
    }
    __syncthreads();

    for (int it = 0; it < NTILE; ++it) {
        const int cur = it & 1;
        // ---- issue next-tile loads early (latency hides under compute) ----
        bf16x8 n0, n1, n2, n3;
        if (it + 1 < NTILE) {
            const char* img = wsb + (size_t)(it + 1) * PAIR_BYTES;
            n0 = *(const bf16x8*)(img + t * 16);
            n1 = *(const bf16x8*)(img + 4096 + t * 16);
            n2 = *(const bf16x8*)(img + 8192 + t * 16);
            n3 = *(const bf16x8*)(img + 12288 + t * 16);
        }

        const char* kb = kbuf[cur];
        const char* vb = vbuf[cur];

        // ---- hoist K fragments for this tile ----
        bf16x8 kf[4][2];
#pragma unroll
        for (int kt = 0; kt < 4; ++kt) {
            const int krow = kt * 16 + lid;
#pragma unroll
            for (int kc = 0; kc < 2; ++kc)
                kf[kt][kc] = *(const bf16x8*)&kb[swz(krow, krow * 128 + (kc * 32 + lgrp * 8) * 2)];
        }

#pragma unroll
        for (int rt = 0; rt < 2; ++rt) {
            // ---- S = Q K^T (scores in exp2 domain) ----
            f32x4 s[4];
            __builtin_amdgcn_s_setprio(1);
#pragma unroll
            for (int kt = 0; kt < 4; ++kt) {
                f32x4 z = {0.f, 0.f, 0.f, 0.f};
#pragma unroll
                for (int kc = 0; kc < 2; ++kc)
                    z = __builtin_amdgcn_mfma_f32_16x16x32_bf16(qf[rt][kc], kf[kt][kc], z, 0, 0, 0);
                s[kt] = z;
            }
            __builtin_amdgcn_s_setprio(0);

            // ---- online softmax (row = lgrp*4 + r, col = kt*16+lid) ----
            char* pl = p_lds[wave][rt];
#pragma unroll
            for (int r = 0; r < 4; ++r) {
                float mx = fmaxf(fmaxf(s[0][r], s[1][r]), fmaxf(s[2][r], s[3][r]));
                mx = fmaxf(mx, __shfl_xor(mx, 1));
                mx = fmaxf(mx, __shfl_xor(mx, 2));
                mx = fmaxf(mx, __shfl_xor(mx, 4));
                mx = fmaxf(mx, __shfl_xor(mx, 8));
                const float mold = m[rt][r];
                const float mnew = fmaxf(mold, mx);
                const float alpha = fexp2(mold - mnew);
                const int prow = lgrp * 4 + r;
                float psum = 0.f;
#pragma unroll
                for (int kt = 0; kt < 4; ++kt) {
                    float p = fexp2(s[kt][r] - mnew);
                    psum += p;
                    *(__bf16*)&pl[swz(prow, prow * 128 + (kt * 16 + lid) * 2)] = (__bf16)p;
                }
                psum += __shfl_xor(psum, 1);
                psum += __shfl_xor(psum, 2);
                psum += __shfl_xor(psum, 4);
                psum += __shfl_xor(psum, 8);
                l[rt][r] = l[rt][r] * alpha + psum;
                m[rt][r] = mnew;
#pragma unroll
                for (int ct = 0; ct < 4; ++ct)
                    acc[rt][ct][r] *= alpha;
            }
        }

        // ---- O += P V (V-frags shared across both row tiles) ----
        bf16x8 pf[2][2];
#pragma unroll
        for (int rt = 0; rt < 2; ++rt)
#pragma unroll
            for (int kc = 0; kc < 2; ++kc)
                pf[rt][kc] = *(const bf16x8*)&p_lds[wave][rt][swz(lid, lid * 128 + (kc * 32 + lgrp * 8) * 2)];
        __builtin_amdgcn_s_setprio(1);
#pragma unroll
        for (int kc = 0; kc < 2; ++kc)
#pragma unroll
            for (int ct = 0; ct < 4; ++ct) {
                const int vrow = ct * 16 + lid;
                bf16x8 vf = *(const bf16x8*)&vb[swz(vrow, vrow * 128 + (kc * 32 + lgrp * 8) * 2)];
#pragma unroll
                for (int rt = 0; rt < 2; ++rt)
                    acc[rt][ct] = __builtin_amdgcn_mfma_f32_16x16x32_bf16(pf[rt][kc], vf, acc[rt][ct], 0, 0, 0);
            }
        __builtin_amdgcn_s_setprio(0);

        // ---- write next tile into the other buffer, then barrier ----
        if (it + 1 < NTILE) {
            const int nxt = cur ^ 1;
            *(bf16x8*)&kbuf[nxt][t * 16] = n0;
            *(bf16x8*)&kbuf[nxt][4096 + t * 16] = n1;
            *(bf16x8*)&vbuf[nxt][t * 16] = n2;
            *(bf16x8*)&vbuf[nxt][4096 + t * 16] = n3;
        }
        __syncthreads();
    }

    // ---- epilogue: normalize and store f32 ----
#pragma unroll
    for (int rt = 0; rt < 2; ++rt)
#pragma unroll
        for (int r = 0; r < 4; ++r) {
            const float inv = 1.f / l[rt][r];
            const int row = q0 + wave * QPW + rt * 16 + lgrp * 4 + r;
            float* dst = Op + (size_t)row * HD + lid;
#pragma unroll
            for (int ct = 0; ct < 4; ++ct)
                dst[ct * 16] = acc[rt][ct][r] * inv;
        }
}

// ---------------- fallback (R1 kernel, no workspace needed) ----------------
__global__ __launch_bounds__(256, 2)
void attn_fwd_kernel(const float* __restrict__ x, float* __restrict__ out) {
    __shared__ __align__(16) char k_lds[KVB * HD * 2];
    __shared__ __align__(16) char vt_lds[HD * KVB * 2];
    __shared__ __align__(16) char p_lds[4][2][16 * KVB * 2];

    const int bh = blockIdx.y;
    const int q0 = blockIdx.x * QPB;
    const float* __restrict__ X = x + (size_t)bh * SEQ * HD;
    float* __restrict__ Op = out + (size_t)bh * SEQ * HD;

    const int t = threadIdx.x;
    const int wave = t >> 6;
    const int lane = t & 63;
    const int lgrp = lane >> 4;
    const int lid = lane & 15;

    bf16x8 qf[2][2];
#pragma unroll
    for (int rt = 0; rt < 2; ++rt) {
        const int row = q0 + wave * QPW + rt * 16 + lid;
#pragma unroll
        for (int kc = 0; kc < 2; ++kc) {
            const float* src = X + (size_t)row * HD + kc * 32 + lgrp * 8;
            float4 a = *(const float4*)src;
            float4 b = *(const float4*)(src + 4);
            bf16x8 f;
            f[0] = (__bf16)a.x; f[1] = (__bf16)a.y; f[2] = (__bf16)a.z; f[3] = (__bf16)a.w;
            f[4] = (__bf16)b.x; f[5] = (__bf16)b.y; f[6] = (__bf16)b.z; f[7] = (__bf16)b.w;
            qf[rt][kc] = f;
        }
    }

    f32x4 acc[2][4];
    float m[2][4], l[2][4];
#pragma unroll
    for (int rt = 0; rt < 2; ++rt)
#pragma unroll
        for (int i = 0; i < 4; ++i) {
            acc[rt][i][0] = 0.f; acc[rt][i][1] = 0.f;
            acc[rt][i][2] = 0.f; acc[rt][i][3] = 0.f;
            m[rt][i] = -1e30f;
            l[rt][i] = 0.f;
        }

    const int srow = t >> 2;
    const int scq = (t & 3) * 16;

    for (int kv0 = 0; kv0 < SEQ; kv0 += KVB) {
        {
            const float* src = X + (size_t)(kv0 + srow) * HD + scq;
            float4 a = *(const float4*)(src);
            float4 b = *(const float4*)(src + 4);
            float4 c = *(const float4*)(src + 8);
            float4 d = *(const float4*)(src + 12);
            bf16x8 f0, f1;
            f0[0] = (__bf16)a.x; f0[1] = (__bf16)a.y; f0[2] = (__bf16)a.z; f0[3] = (__bf16)a.w;
            f0[4] = (__bf16)b.x; f0[5] = (__bf16)b.y; f0[6] = (__bf16)b.z; f0[7] = (__bf16)b.w;
            f1[0] = (__bf16)c.x; f1[1] = (__bf16)c.y; f1[2] = (__bf16)c.z; f1[3] = (__bf16)c.w;
            f1[4] = (__bf16)d.x; f1[5] = (__bf16)d.y; f1[6] = (__bf16)d.z; f1[7] = (__bf16)d.w;
            *(bf16x8*)&k_lds[swz(srow, srow * 128 + scq * 2)] = f0;
            *(bf16x8*)&k_lds[swz(srow, srow * 128 + scq * 2 + 16)] = f1;
        }
        {
            bf16x8 g0, g1;
#pragma unroll
            for (int j = 0; j < 8; ++j)
                g0[j] = (__bf16)X[(size_t)(kv0 + scq + j) * HD + srow];
#pragma unroll
            for (int j = 0; j < 8; ++j)
                g1[j] = (__bf16)X[(size_t)(kv0 + scq + 8 + j) * HD + srow];
            *(bf16x8*)&vt_lds[swz(srow, srow * 128 + scq * 2)] = g0;
            *(bf16x8*)&vt_lds[swz(srow, srow * 128 + scq * 2 + 16)] = g1;
        }
        __syncthreads();

#pragma unroll
        for (int rt = 0; rt < 2; ++rt) {
            f32x4 s[4];
#pragma unroll
            for (int kt = 0; kt < 4; ++kt) {
                f32x4 z = {0.f, 0.f, 0.f, 0.f};
#pragma unroll
                for (int kc = 0; kc < 2; ++kc) {
                    const int krow = kt * 16 + lid;
                    bf16x8 kfr = *(const bf16x8*)&k_lds[swz(krow, krow * 128 + (kc * 32 + lgrp * 8) * 2)];
                    z = __builtin_amdgcn_mfma_f32_16x16x32_bf16(qf[rt][kc], kfr, z, 0, 0, 0);
                }
                s[kt] = z;
            }

            char* pl = p_lds[wave][rt];
#pragma unroll
            for (int r = 0; r < 4; ++r) {
                float mx = fmaxf(fmaxf(s[0][r], s[1][r]), fmaxf(s[2][r], s[3][r]));
                mx = fmaxf(mx, __shfl_xor(mx, 1));
                mx = fmaxf(mx, __shfl_xor(mx, 2));
                mx = fmaxf(mx, __shfl_xor(mx, 4));
                mx = fmaxf(mx, __shfl_xor(mx, 8));
                const float mold = m[rt][r];
                const float mnew = fmaxf(mold, mx);
                const float alpha = __expf(mold - mnew);
                const int prow = lgrp * 4 + r;
                float psum = 0.f;
#pragma unroll
                for (int kt = 0; kt < 4; ++kt) {
                    float p = __expf(s[kt][r] - mnew);
                    psum += p;
                    *(__bf16*)&pl[swz(prow, prow * 128 + (kt * 16 + lid) * 2)] = (__bf16)p;
                }
                psum += __shfl_xor(psum, 1);
                psum += __shfl_xor(psum, 2);
                psum += __shfl_xor(psum, 4);
                psum += __shfl_xor(psum, 8);
                l[rt][r] = l[rt][r] * alpha + psum;
                m[rt][r] = mnew;
#pragma unroll
                for (int ct = 0; ct < 4; ++ct)
                    acc[rt][ct][r] *= alpha;
            }

#pragma unroll
            for (int kc = 0; kc < 2; ++kc) {
                bf16x8 pfr = *(const bf16x8*)&pl[swz(lid, lid * 128 + (kc * 32 + lgrp * 8) * 2)];
#pragma unroll
                for (int ct = 0; ct < 4; ++ct) {
                    const int vrow = ct * 16 + lid;
                    bf16x8 vf = *(const bf16x8*)&vt_lds[swz(vrow, vrow * 128 + (kc * 32 + lgrp * 8) * 2)];
                    acc[rt][ct] = __builtin_amdgcn_mfma_f32_16x16x32_bf16(pfr, vf, acc[rt][ct], 0, 0, 0);
                }
            }
        }
        __syncthreads();
    }

#pragma unroll
    for (int rt = 0; rt < 2; ++rt)
#pragma unroll
        for (int r = 0; r < 4; ++r) {
            const float inv = 1.f / l[rt][r];
            const int row = q0 + wave * QPW + rt * 16 + lgrp * 4 + r;
            float* dst = Op + (size_t)row * HD + lid;
#pragma unroll
            for (int ct = 0; ct < 4; ++ct)
                dst[ct * 16] = acc[rt][ct][r] * inv;
        }
}

extern "C" void kernel_launch(void* const* d_in, const int* in_sizes, int n_in,
                              void* d_out, int out_size, void* d_ws, size_t ws_size,
                              hipStream_t stream) {
    const float* x = (const float*)d_in[0];
    float* out = (float*)d_out;
    if (ws_size >= WS_NEEDED) {
        char* ws = (char*)d_ws;
        dim3 pgrid(NTILE, NBH);
        hipLaunchKernelGGL(prep_kernel, pgrid, dim3(256), 0, stream, x, ws);
        dim3 agrid(SEQ / QPB, NBH);
        hipLaunchKernelGGL(attn2_kernel, agrid, dim3(256), 0, stream, x, ws, out);
    } else {
        dim3 grid(SEQ / QPB, NBH);
        hipLaunchKernelGGL(attn_fwd_kernel, grid, dim3(256), 0, stream, x, out);
    }
}

// Round 3
// 115.658 us; speedup vs baseline: 1.3869x; 1.0321x over previous
//
#include <hip/hip_runtime.h>
#include <hip/hip_bf16.h>
#include <stdint.h>

// MatmulAttention: x = [2,16,2048,64] f32, q=k=v=x, no 1/sqrt(d) scale.
// out = softmax(q k^T) v, f32.
// R3: occupancy push. QPB=64 (1024 blocks = 4/CU), LDS 40KB, lb(256,4);
// staging via global_load_lds DMA from pre-swizzled images; defer-max (T13).

typedef __bf16 bf16x8 __attribute__((ext_vector_type(8)));
typedef float f32x4 __attribute__((ext_vector_type(4)));

#define SEQ 2048
#define HD 64
#define KVB 64
#define NBH 32
#define NTILE (SEQ / KVB)        // 32 kv tiles
#define IMG_BYTES 8192           // one 64x64 bf16 tile image
#define PAIR_BYTES 16384         // K image + VT image
#define WS_NEEDED ((size_t)NBH * NTILE * PAIR_BYTES)  // 16 MB

#define QPB 64   // q rows per block (16 per wave)
#define RESCALE_THR 8.0f

// XOR swizzle: spreads 128B-stride rows across banks for 16B LDS accesses.
__device__ __forceinline__ int swz(int row, int byteoff) {
    return byteoff ^ ((row & 7) << 4);
}

__device__ __forceinline__ float fexp2(float x) {
    float r;
    asm("v_exp_f32 %0, %1" : "=v"(r) : "v"(x));
    return r;
}

#if __has_builtin(__builtin_amdgcn_global_load_lds)
#define HAVE_GLLDS 1
typedef const __attribute__((address_space(1))) unsigned int* gas_t;
typedef __attribute__((address_space(3))) unsigned int* las_t;
__device__ __forceinline__ void gl_lds16(const void* g, void* l) {
    __builtin_amdgcn_global_load_lds((gas_t)g, (las_t)l, 16, 0, 0);
}
#else
#define HAVE_GLLDS 0
#endif

// ---------------- prepass: build bf16 tile images ----------------
__global__ __launch_bounds__(256)
void prep_kernel(const float* __restrict__ x, char* __restrict__ ws) {
    const int bh = blockIdx.y;
    const int tile = blockIdx.x;
    const int kv0 = tile * KVB;
    const int t = threadIdx.x;
    const int srow = t >> 2;        // 0..63
    const int scq = (t & 3) * 16;   // 0,16,32,48
    const float* __restrict__ X = x + (size_t)bh * SEQ * HD;
    char* __restrict__ img = ws + ((size_t)bh * NTILE + tile) * PAIR_BYTES;

    // K image: [kv][d] bf16, swizzled rows
    {
        const float* src = X + (size_t)(kv0 + srow) * HD + scq;
        float4 a = *(const float4*)(src);
        float4 b = *(const float4*)(src + 4);
        float4 c = *(const float4*)(src + 8);
        float4 d = *(const float4*)(src + 12);
        bf16x8 f0, f1;
        f0[0] = (__bf16)a.x; f0[1] = (__bf16)a.y; f0[2] = (__bf16)a.z; f0[3] = (__bf16)a.w;
        f0[4] = (__bf16)b.x; f0[5] = (__bf16)b.y; f0[6] = (__bf16)b.z; f0[7] = (__bf16)b.w;
        f1[0] = (__bf16)c.x; f1[1] = (__bf16)c.y; f1[2] = (__bf16)c.z; f1[3] = (__bf16)c.w;
        f1[4] = (__bf16)d.x; f1[5] = (__bf16)d.y; f1[6] = (__bf16)d.z; f1[7] = (__bf16)d.w;
        *(bf16x8*)&img[swz(srow, srow * 128 + scq * 2)] = f0;
        *(bf16x8*)&img[swz(srow, srow * 128 + scq * 2 + 16)] = f1;
    }
    // VT image: [d][kv] bf16, swizzled rows (row = d = srow, col = kv)
    {
        bf16x8 g0, g1;
#pragma unroll
        for (int j = 0; j < 8; ++j)
            g0[j] = (__bf16)X[(size_t)(kv0 + scq + j) * HD + srow];
#pragma unroll
        for (int j = 0; j < 8; ++j)
            g1[j] = (__bf16)X[(size_t)(kv0 + scq + 8 + j) * HD + srow];
        *(bf16x8*)&img[IMG_BYTES + swz(srow, srow * 128 + scq * 2)] = g0;
        *(bf16x8*)&img[IMG_BYTES + swz(srow, srow * 128 + scq * 2 + 16)] = g1;
    }
}

// ---------------- main fused attention (image-fed, 4 blocks/CU) ----------------
__global__ __launch_bounds__(256, 4)
void attn3_kernel(const float* __restrict__ x, const char* __restrict__ ws,
                  float* __restrict__ out) {
    __shared__ __align__(16) char kbuf[2][IMG_BYTES];
    __shared__ __align__(16) char vbuf[2][IMG_BYTES];
    __shared__ __align__(16) char p_lds[4][16 * KVB * 2];

    const int bh = blockIdx.y;
    const int q0 = blockIdx.x * QPB;
    const float* __restrict__ X = x + (size_t)bh * SEQ * HD;
    float* __restrict__ Op = out + (size_t)bh * SEQ * HD;
    const char* __restrict__ wsb = ws + (size_t)bh * NTILE * PAIR_BYTES;

    const int t = threadIdx.x;
    const int wave = t >> 6;
    const int lane = t & 63;
    const int lgrp = lane >> 4;
    const int lid = lane & 15;

    // ---- hoist Q fragments, pre-scaled by log2(e) (exp2-domain softmax) ----
    const float SCL = 1.4426950408889634f;
    bf16x8 qf[2];
    {
        const int row = q0 + wave * 16 + lid;
#pragma unroll
        for (int kc = 0; kc < 2; ++kc) {
            const float* src = X + (size_t)row * HD + kc * 32 + lgrp * 8;
            float4 a = *(const float4*)src;
            float4 b = *(const float4*)(src + 4);
            bf16x8 f;
            f[0] = (__bf16)(a.x * SCL); f[1] = (__bf16)(a.y * SCL);
            f[2] = (__bf16)(a.z * SCL); f[3] = (__bf16)(a.w * SCL);
            f[4] = (__bf16)(b.x * SCL); f[5] = (__bf16)(b.y * SCL);
            f[6] = (__bf16)(b.z * SCL); f[7] = (__bf16)(b.w * SCL);
            qf[kc] = f;
        }
    }

    f32x4 acc[4];
    float m[4], l[4];
#pragma unroll
    for (int i = 0; i < 4; ++i) {
        acc[i][0] = 0.f; acc[i][1] = 0.f; acc[i][2] = 0.f; acc[i][3] = 0.f;
        m[i] = -1e30f;
        l[i] = 0.f;
    }

    // ---- prologue: stage tile 0 (wave w copies 4KB chunk w of the 16KB pair)
#if HAVE_GLLDS
    {
        char* base = (wave & 2) ? &vbuf[0][(wave & 1) * 4096] : &kbuf[0][(wave & 1) * 4096];
        const char* sp = wsb + wave * 4096 + lane * 16;
#pragma unroll
        for (int j = 0; j < 4; ++j)
            gl_lds16(sp + j * 1024, base + j * 1024);
    }
#else
    {
        const char* img = wsb;
#pragma unroll
        for (int q = 0; q < 4; ++q) {
            bf16x8 d0 = *(const bf16x8*)(img + q * 4096 + t * 16);
            char* dst = (q & 2) ? &vbuf[0][(q & 1) * 4096] : &kbuf[0][(q & 1) * 4096];
            *(bf16x8*)&dst[t * 16] = d0;
        }
    }
#endif
    __syncthreads();

    for (int it = 0; it < NTILE; ++it) {
        const int cur = it & 1;

        // ---- async-stage next tile into the other buffer (overlaps compute)
#if HAVE_GLLDS
        if (it + 1 < NTILE) {
            const char* img = wsb + (size_t)(it + 1) * PAIR_BYTES;
            char* base = (wave & 2) ? &vbuf[cur ^ 1][(wave & 1) * 4096]
                                    : &kbuf[cur ^ 1][(wave & 1) * 4096];
            const char* sp = img + wave * 4096 + lane * 16;
#pragma unroll
            for (int j = 0; j < 4; ++j)
                gl_lds16(sp + j * 1024, base + j * 1024);
        }
#else
        bf16x8 n0, n1, n2, n3;
        if (it + 1 < NTILE) {
            const char* img = wsb + (size_t)(it + 1) * PAIR_BYTES;
            n0 = *(const bf16x8*)(img + t * 16);
            n1 = *(const bf16x8*)(img + 4096 + t * 16);
            n2 = *(const bf16x8*)(img + 8192 + t * 16);
            n3 = *(const bf16x8*)(img + 12288 + t * 16);
        }
#endif

        const char* kb = kbuf[cur];
        const char* vb = vbuf[cur];

        // ---- K fragments ----
        bf16x8 kf[4][2];
#pragma unroll
        for (int kt = 0; kt < 4; ++kt) {
            const int krow = kt * 16 + lid;
#pragma unroll
            for (int kc = 0; kc < 2; ++kc)
                kf[kt][kc] = *(const bf16x8*)&kb[swz(krow, krow * 128 + (kc * 32 + lgrp * 8) * 2)];
        }

        // ---- S = Q K^T (scores in exp2 domain) ----
        f32x4 sc[4];
        __builtin_amdgcn_s_setprio(1);
#pragma unroll
        for (int kt = 0; kt < 4; ++kt) {
            f32x4 z = {0.f, 0.f, 0.f, 0.f};
#pragma unroll
            for (int kc = 0; kc < 2; ++kc)
                z = __builtin_amdgcn_mfma_f32_16x16x32_bf16(qf[kc], kf[kt][kc], z, 0, 0, 0);
            sc[kt] = z;
        }
        __builtin_amdgcn_s_setprio(0);

        // ---- online softmax with defer-max (rows = lgrp*4+r, cols = kt*16+lid)
        float mx[4];
#pragma unroll
        for (int r = 0; r < 4; ++r) {
            float v = fmaxf(fmaxf(sc[0][r], sc[1][r]), fmaxf(sc[2][r], sc[3][r]));
            v = fmaxf(v, __shfl_xor(v, 1));
            v = fmaxf(v, __shfl_xor(v, 2));
            v = fmaxf(v, __shfl_xor(v, 4));
            v = fmaxf(v, __shfl_xor(v, 8));
            mx[r] = v;
        }
        int need = 0;
#pragma unroll
        for (int r = 0; r < 4; ++r)
            need |= (mx[r] > m[r] + RESCALE_THR) ? 1 : 0;
        if (__any(need)) {
#pragma unroll
            for (int r = 0; r < 4; ++r) {
                const float mnew = fmaxf(m[r], mx[r]);
                const float alpha = fexp2(m[r] - mnew);
                l[r] *= alpha;
                m[r] = mnew;
#pragma unroll
                for (int ct = 0; ct < 4; ++ct)
                    acc[ct][r] *= alpha;
            }
        }
        char* pl = p_lds[wave];
#pragma unroll
        for (int r = 0; r < 4; ++r) {
            const int prow = lgrp * 4 + r;
            float psum = 0.f;
#pragma unroll
            for (int kt = 0; kt < 4; ++kt) {
                float p = fexp2(sc[kt][r] - m[r]);
                psum += p;
                *(__bf16*)&pl[swz(prow, prow * 128 + (kt * 16 + lid) * 2)] = (__bf16)p;
            }
            psum += __shfl_xor(psum, 1);
            psum += __shfl_xor(psum, 2);
            psum += __shfl_xor(psum, 4);
            psum += __shfl_xor(psum, 8);
            l[r] += psum;
        }

        // ---- O += P V ----
        bf16x8 pf[2];
#pragma unroll
        for (int kc = 0; kc < 2; ++kc)
            pf[kc] = *(const bf16x8*)&pl[swz(lid, lid * 128 + (kc * 32 + lgrp * 8) * 2)];
        __builtin_amdgcn_s_setprio(1);
#pragma unroll
        for (int kc = 0; kc < 2; ++kc)
#pragma unroll
            for (int ct = 0; ct < 4; ++ct) {
                const int vrow = ct * 16 + lid;
                bf16x8 vf = *(const bf16x8*)&vb[swz(vrow, vrow * 128 + (kc * 32 + lgrp * 8) * 2)];
                acc[ct] = __builtin_amdgcn_mfma_f32_16x16x32_bf16(pf[kc], vf, acc[ct], 0, 0, 0);
            }
        __builtin_amdgcn_s_setprio(0);

#if !HAVE_GLLDS
        if (it + 1 < NTILE) {
            const int nxt = cur ^ 1;
            *(bf16x8*)&kbuf[nxt][t * 16] = n0;
            *(bf16x8*)&kbuf[nxt][4096 + t * 16] = n1;
            *(bf16x8*)&vbuf[nxt][t * 16] = n2;
            *(bf16x8*)&vbuf[nxt][4096 + t * 16] = n3;
        }
#endif
        __syncthreads();
    }

    // ---- epilogue: normalize and store f32 ----
#pragma unroll
    for (int r = 0; r < 4; ++r) {
        const float inv = 1.f / l[r];
        const int row = q0 + wave * 16 + lgrp * 4 + r;
        float* dst = Op + (size_t)row * HD + lid;
#pragma unroll
        for (int ct = 0; ct < 4; ++ct)
            dst[ct * 16] = acc[ct][r] * inv;
    }
}

// ---------------- fallback (R1 kernel, no workspace needed) ----------------
__global__ __launch_bounds__(256, 2)
void attn_fwd_kernel(const float* __restrict__ x, float* __restrict__ out) {
    __shared__ __align__(16) char k_lds[KVB * HD * 2];
    __shared__ __align__(16) char vt_lds[HD * KVB * 2];
    __shared__ __align__(16) char p_lds2[4][2][16 * KVB * 2];

    const int bh = blockIdx.y;
    const int q0 = blockIdx.x * 128;
    const float* __restrict__ X = x + (size_t)bh * SEQ * HD;
    float* __restrict__ Op = out + (size_t)bh * SEQ * HD;

    const int t = threadIdx.x;
    const int wave = t >> 6;
    const int lane = t & 63;
    const int lgrp = lane >> 4;
    const int lid = lane & 15;

    bf16x8 qf[2][2];
#pragma unroll
    for (int rt = 0; rt < 2; ++rt) {
        const int row = q0 + wave * 32 + rt * 16 + lid;
#pragma unroll
        for (int kc = 0; kc < 2; ++kc) {
            const float* src = X + (size_t)row * HD + kc * 32 + lgrp * 8;
            float4 a = *(const float4*)src;
            float4 b = *(const float4*)(src + 4);
            bf16x8 f;
            f[0] = (__bf16)a.x; f[1] = (__bf16)a.y; f[2] = (__bf16)a.z; f[3] = (__bf16)a.w;
            f[4] = (__bf16)b.x; f[5] = (__bf16)b.y; f[6] = (__bf16)b.z; f[7] = (__bf16)b.w;
            qf[rt][kc] = f;
        }
    }

    f32x4 acc[2][4];
    float m[2][4], l[2][4];
#pragma unroll
    for (int rt = 0; rt < 2; ++rt)
#pragma unroll
        for (int i = 0; i < 4; ++i) {
            acc[rt][i][0] = 0.f; acc[rt][i][1] = 0.f;
            acc[rt][i][2] = 0.f; acc[rt][i][3] = 0.f;
            m[rt][i] = -1e30f;
            l[rt][i] = 0.f;
        }

    const int srow = t >> 2;
    const int scq = (t & 3) * 16;

    for (int kv0 = 0; kv0 < SEQ; kv0 += KVB) {
        {
            const float* src = X + (size_t)(kv0 + srow) * HD + scq;
            float4 a = *(const float4*)(src);
            float4 b = *(const float4*)(src + 4);
            float4 c = *(const float4*)(src + 8);
            float4 d = *(const float4*)(src + 12);
            bf16x8 f0, f1;
            f0[0] = (__bf16)a.x; f0[1] = (__bf16)a.y; f0[2] = (__bf16)a.z; f0[3] = (__bf16)a.w;
            f0[4] = (__bf16)b.x; f0[5] = (__bf16)b.y; f0[6] = (__bf16)b.z; f0[7] = (__bf16)b.w;
            f1[0] = (__bf16)c.x; f1[1] = (__bf16)c.y; f1[2] = (__bf16)c.z; f1[3] = (__bf16)c.w;
            f1[4] = (__bf16)d.x; f1[5] = (__bf16)d.y; f1[6] = (__bf16)d.z; f1[7] = (__bf16)d.w;
            *(bf16x8*)&k_lds[swz(srow, srow * 128 + scq * 2)] = f0;
            *(bf16x8*)&k_lds[swz(srow, srow * 128 + scq * 2 + 16)] = f1;
        }
        {
            bf16x8 g0, g1;
#pragma unroll
            for (int j = 0; j < 8; ++j)
                g0[j] = (__bf16)X[(size_t)(kv0 + scq + j) * HD + srow];
#pragma unroll
            for (int j = 0; j < 8; ++j)
                g1[j] = (__bf16)X[(size_t)(kv0 + scq + 8 + j) * HD + srow];
            *(bf16x8*)&vt_lds[swz(srow, srow * 128 + scq * 2)] = g0;
            *(bf16x8*)&vt_lds[swz(srow, srow * 128 + scq * 2 + 16)] = g1;
        }
        __syncthreads();

#pragma unroll
        for (int rt = 0; rt < 2; ++rt) {
            f32x4 s[4];
#pragma unroll
            for (int kt = 0; kt < 4; ++kt) {
                f32x4 z = {0.f, 0.f, 0.f, 0.f};
#pragma unroll
                for (int kc = 0; kc < 2; ++kc) {
                    const int krow = kt * 16 + lid;
                    bf16x8 kfr = *(const bf16x8*)&k_lds[swz(krow, krow * 128 + (kc * 32 + lgrp * 8) * 2)];
                    z = __builtin_amdgcn_mfma_f32_16x16x32_bf16(qf[rt][kc], kfr, z, 0, 0, 0);
                }
                s[kt] = z;
            }

            char* pl = p_lds2[wave][rt];
#pragma unroll
            for (int r = 0; r < 4; ++r) {
                float mxv = fmaxf(fmaxf(s[0][r], s[1][r]), fmaxf(s[2][r], s[3][r]));
                mxv = fmaxf(mxv, __shfl_xor(mxv, 1));
                mxv = fmaxf(mxv, __shfl_xor(mxv, 2));
                mxv = fmaxf(mxv, __shfl_xor(mxv, 4));
                mxv = fmaxf(mxv, __shfl_xor(mxv, 8));
                const float mold = m[rt][r];
                const float mnew = fmaxf(mold, mxv);
                const float alpha = __expf(mold - mnew);
                const int prow = lgrp * 4 + r;
                float psum = 0.f;
#pragma unroll
                for (int kt = 0; kt < 4; ++kt) {
                    float p = __expf(s[kt][r] - mnew);
                    psum += p;
                    *(__bf16*)&pl[swz(prow, prow * 128 + (kt * 16 + lid) * 2)] = (__bf16)p;
                }
                psum += __shfl_xor(psum, 1);
                psum += __shfl_xor(psum, 2);
                psum += __shfl_xor(psum, 4);
                psum += __shfl_xor(psum, 8);
                l[rt][r] = l[rt][r] * alpha + psum;
                m[rt][r] = mnew;
#pragma unroll
                for (int ct = 0; ct < 4; ++ct)
                    acc[rt][ct][r] *= alpha;
            }

#pragma unroll
            for (int kc = 0; kc < 2; ++kc) {
                bf16x8 pfr = *(const bf16x8*)&pl[swz(lid, lid * 128 + (kc * 32 + lgrp * 8) * 2)];
#pragma unroll
                for (int ct = 0; ct < 4; ++ct) {
                    const int vrow = ct * 16 + lid;
                    bf16x8 vf = *(const bf16x8*)&vt_lds[swz(vrow, vrow * 128 + (kc * 32 + lgrp * 8) * 2)];
                    acc[rt][ct] = __builtin_amdgcn_mfma_f32_16x16x32_bf16(pfr, vf, acc[rt][ct], 0, 0, 0);
                }
            }
        }
        __syncthreads();
    }

#pragma unroll
    for (int rt = 0; rt < 2; ++rt)
#pragma unroll
        for (int r = 0; r < 4; ++r) {
            const float inv = 1.f / l[rt][r];
            const int row = q0 + wave * 32 + rt * 16 + lgrp * 4 + r;
            float* dst = Op + (size_t)row * HD + lid;
#pragma unroll
            for (int ct = 0; ct < 4; ++ct)
                dst[ct * 16] = acc[rt][ct][r] * inv;
        }
}

extern "C" void kernel_launch(void* const* d_in, const int* in_sizes, int n_in,
                              void* d_out, int out_size, void* d_ws, size_t ws_size,
                              hipStream_t stream) {
    const float* x = (const float*)d_in[0];
    float* out = (float*)d_out;
    if (ws_size >= WS_NEEDED) {
        char* ws = (char*)d_ws;
        dim3 pgrid(NTILE, NBH);
        hipLaunchKernelGGL(prep_kernel, pgrid, dim3(256), 0, stream, x, ws);
        dim3 agrid(SEQ / QPB, NBH);
        hipLaunchKernelGGL(attn3_kernel, agrid, dim3(256), 0, stream, x, ws, out);
    } else {
        dim3 grid(SEQ / 128, NBH);
        hipLaunchKernelGGL(attn_fwd_kernel, grid, dim3(256), 0, stream, x, out);
    }
}

// Round 4
// 70.056 us; speedup vs baseline: 2.2896x; 1.6509x over previous
//
#include <hip/hip_runtime.h>
#include <hip/hip_bf16.h>
#include <stdint.h>

// MatmulAttention: x = [2,16,2048,64] f32, q=k=v=x, no 1/sqrt(d) scale.
// out = softmax(q k^T) v, f32.
// R4: swapped-QK^T 32x32 structure (m214-style): S^T = mfma(K,Q) puts a full
// P-row per lane -> lane-local softmax (1 shfl), in-register P->PA via
// cvt_pk + v_permlane32_swap_b32 (T12), defer-max THR=20 (T13), prepass
// images + global_load_lds dbuf staging, T1 XCD swizzle.

typedef __bf16 bf16x8 __attribute__((ext_vector_type(8)));
typedef __bf16 bf16x2 __attribute__((ext_vector_type(2)));
typedef float f32x4 __attribute__((ext_vector_type(4)));
typedef float f32x16 __attribute__((ext_vector_type(16)));
typedef unsigned int u32x4v __attribute__((ext_vector_type(4)));

#define SEQ 2048
#define HD 64
#define KVB 64
#define NBH 32
#define NTILE (SEQ / KVB)        // 32 kv tiles
#define IMG_BYTES 8192           // one 64x64 bf16 tile image
#define PAIR_BYTES 16384         // K image + VT image
#define WS_NEEDED ((size_t)NBH * NTILE * PAIR_BYTES)  // 16 MB

#define QPB 128                  // q rows per block (32 per wave, 4 waves)
#define RESCALE_THR 20.0f        // exp2-domain defer-max threshold

// XOR swizzle: spreads 128B-stride rows across banks for 16B LDS accesses.
__device__ __forceinline__ int swz(int row, int byteoff) {
    return byteoff ^ ((row & 7) << 4);
}

__device__ __forceinline__ float fexp2(float x) {
    float r;
    asm("v_exp_f32 %0, %1" : "=v"(r) : "v"(x));
    return r;
}

__device__ __forceinline__ unsigned pk_bf16(float a, float b) {
    bf16x2 v;
    v[0] = (__bf16)a;
    v[1] = (__bf16)b;
    return __builtin_bit_cast(unsigned, v);
}

#if __has_builtin(__builtin_amdgcn_global_load_lds)
#define HAVE_GLLDS 1
typedef const __attribute__((address_space(1))) unsigned int* gas_t;
typedef __attribute__((address_space(3))) unsigned int* las_t;
__device__ __forceinline__ void gl_lds16(const void* g, void* l) {
    __builtin_amdgcn_global_load_lds((gas_t)g, (las_t)l, 16, 0, 0);
}
#else
#define HAVE_GLLDS 0
#endif

// ---------------- prepass: build bf16 tile images ----------------
__global__ __launch_bounds__(256)
void prep_kernel(const float* __restrict__ x, char* __restrict__ ws) {
    const int bh = blockIdx.y;
    const int tile = blockIdx.x;
    const int kv0 = tile * KVB;
    const int t = threadIdx.x;
    const int srow = t >> 2;        // 0..63
    const int scq = (t & 3) * 16;   // 0,16,32,48
    const float* __restrict__ X = x + (size_t)bh * SEQ * HD;
    char* __restrict__ img = ws + ((size_t)bh * NTILE + tile) * PAIR_BYTES;

    // K image: [kv][d] bf16, swizzled rows
    {
        const float* src = X + (size_t)(kv0 + srow) * HD + scq;
        float4 a = *(const float4*)(src);
        float4 b = *(const float4*)(src + 4);
        float4 c = *(const float4*)(src + 8);
        float4 d = *(const float4*)(src + 12);
        bf16x8 f0, f1;
        f0[0] = (__bf16)a.x; f0[1] = (__bf16)a.y; f0[2] = (__bf16)a.z; f0[3] = (__bf16)a.w;
        f0[4] = (__bf16)b.x; f0[5] = (__bf16)b.y; f0[6] = (__bf16)b.z; f0[7] = (__bf16)b.w;
        f1[0] = (__bf16)c.x; f1[1] = (__bf16)c.y; f1[2] = (__bf16)c.z; f1[3] = (__bf16)c.w;
        f1[4] = (__bf16)d.x; f1[5] = (__bf16)d.y; f1[6] = (__bf16)d.z; f1[7] = (__bf16)d.w;
        *(bf16x8*)&img[swz(srow, srow * 128 + scq * 2)] = f0;
        *(bf16x8*)&img[swz(srow, srow * 128 + scq * 2 + 16)] = f1;
    }
    // VT image: [d][kv] bf16, swizzled rows (row = d = srow, col = kv)
    {
        bf16x8 g0, g1;
#pragma unroll
        for (int j = 0; j < 8; ++j)
            g0[j] = (__bf16)X[(size_t)(kv0 + scq + j) * HD + srow];
#pragma unroll
        for (int j = 0; j < 8; ++j)
            g1[j] = (__bf16)X[(size_t)(kv0 + scq + 8 + j) * HD + srow];
        *(bf16x8*)&img[IMG_BYTES + swz(srow, srow * 128 + scq * 2)] = g0;
        *(bf16x8*)&img[IMG_BYTES + swz(srow, srow * 128 + scq * 2 + 16)] = g1;
    }
}

// ---------------- main fused attention (32x32 swapped-QK^T) ----------------
__global__ __launch_bounds__(256, 2)
void attn4_kernel(const float* __restrict__ x, const char* __restrict__ ws,
                  float* __restrict__ out) {
    __shared__ __align__(16) char kbuf[2][IMG_BYTES];
    __shared__ __align__(16) char vbuf[2][IMG_BYTES];

    // T1 XCD swizzle: 512 blocks, bijective (512 % 8 == 0); same-bh blocks
    // land on the same XCD (4 heads/XCD -> 2MB image set fits 4MB L2).
    const int wg = blockIdx.x;
    const int sid = (wg & 7) * 64 + (wg >> 3);
    const int bh = sid >> 4;
    const int q0 = (sid & 15) * QPB;

    const float* __restrict__ X = x + (size_t)bh * SEQ * HD;
    float* __restrict__ Op = out + (size_t)bh * SEQ * HD;
    const char* __restrict__ wsb = ws + (size_t)bh * NTILE * PAIR_BYTES;

    const int t = threadIdx.x;
    const int wave = t >> 6;
    const int lane = t & 63;
    const int ln = lane & 31;   // q row (own), also S^T/O column index
    const int hi = lane >> 5;   // k-group half

    const int qbase = q0 + wave * 32;

    // ---- hoist Q B-frags: B[d][q]: lane holds q=ln, d = dt*16 + hi*8 + b ----
    const float SCL = 1.4426950408889634f;  // log2(e)
    bf16x8 qf[4];
    {
        const float* qsrc = X + (size_t)(qbase + ln) * HD;
#pragma unroll
        for (int dt = 0; dt < 4; ++dt) {
            const float* s8 = qsrc + dt * 16 + hi * 8;
            float4 a = *(const float4*)s8;
            float4 b = *(const float4*)(s8 + 4);
            bf16x8 f;
            f[0] = (__bf16)(a.x * SCL); f[1] = (__bf16)(a.y * SCL);
            f[2] = (__bf16)(a.z * SCL); f[3] = (__bf16)(a.w * SCL);
            f[4] = (__bf16)(b.x * SCL); f[5] = (__bf16)(b.y * SCL);
            f[6] = (__bf16)(b.z * SCL); f[7] = (__bf16)(b.w * SCL);
            qf[dt] = f;
        }
    }

    f32x16 acc0, acc1;   // O accum: dt=0 -> d=0..31, dt=1 -> d=32..63
#pragma unroll
    for (int i = 0; i < 16; ++i) { acc0[i] = 0.f; acc1[i] = 0.f; }
    float m = -1e30f, l = 0.f;

    // ---- prologue: stage tile 0 (wave w copies 4KB chunk w of 16KB pair) ----
#if HAVE_GLLDS
    {
        char* base = (wave & 2) ? &vbuf[0][(wave & 1) * 4096] : &kbuf[0][(wave & 1) * 4096];
        const char* sp = wsb + wave * 4096 + lane * 16;
#pragma unroll
        for (int j = 0; j < 4; ++j)
            gl_lds16(sp + j * 1024, base + j * 1024);
    }
#else
    {
        const char* img = wsb;
#pragma unroll
        for (int q = 0; q < 4; ++q) {
            bf16x8 d0 = *(const bf16x8*)(img + q * 4096 + t * 16);
            char* dst = (q & 2) ? &vbuf[0][(q & 1) * 4096] : &kbuf[0][(q & 1) * 4096];
            *(bf16x8*)&dst[t * 16] = d0;
        }
    }
#endif
    __syncthreads();

    for (int it = 0; it < NTILE; ++it) {
        const int cur = it & 1;

#if HAVE_GLLDS
        if (it + 1 < NTILE) {
            const char* img = wsb + (size_t)(it + 1) * PAIR_BYTES;
            char* base = (wave & 2) ? &vbuf[cur ^ 1][(wave & 1) * 4096]
                                    : &kbuf[cur ^ 1][(wave & 1) * 4096];
            const char* sp = img + wave * 4096 + lane * 16;
#pragma unroll
            for (int j = 0; j < 4; ++j)
                gl_lds16(sp + j * 1024, base + j * 1024);
        }
#else
        bf16x8 n0, n1, n2, n3;
        if (it + 1 < NTILE) {
            const char* img = wsb + (size_t)(it + 1) * PAIR_BYTES;
            n0 = *(const bf16x8*)(img + t * 16);
            n1 = *(const bf16x8*)(img + 4096 + t * 16);
            n2 = *(const bf16x8*)(img + 8192 + t * 16);
            n3 = *(const bf16x8*)(img + 12288 + t * 16);
        }
#endif

        const char* kb = kbuf[cur];
        const char* vb = vbuf[cur];

        // ---- S^T = mfma(K, Q): D[kv][q], lane: q=ln, rows via reg index ----
        f32x16 s0, s1;
#pragma unroll
        for (int i = 0; i < 16; ++i) { s0[i] = 0.f; s1[i] = 0.f; }
        __builtin_amdgcn_s_setprio(1);
#pragma unroll
        for (int dt = 0; dt < 4; ++dt) {
            const int r0 = ln;
            bf16x8 kf0 = *(const bf16x8*)&kb[swz(r0, r0 * 128 + dt * 32 + hi * 16)];
            s0 = __builtin_amdgcn_mfma_f32_32x32x16_bf16(kf0, qf[dt], s0, 0, 0, 0);
            const int r1 = 32 + ln;
            bf16x8 kf1 = *(const bf16x8*)&kb[swz(r1, r1 * 128 + dt * 32 + hi * 16)];
            s1 = __builtin_amdgcn_mfma_f32_32x32x16_bf16(kf1, qf[dt], s1, 0, 0, 0);
        }
        __builtin_amdgcn_s_setprio(0);

        // ---- lane-local online softmax (row = own q; k = reg-indexed) ----
        float mx = s0[0];
#pragma unroll
        for (int i = 1; i < 16; ++i) mx = fmaxf(mx, s0[i]);
#pragma unroll
        for (int i = 0; i < 16; ++i) mx = fmaxf(mx, s1[i]);
        mx = fmaxf(mx, __shfl_xor(mx, 32));

        if (__any(mx > m + RESCALE_THR)) {
            const float mnew = fmaxf(m, mx);
            const float alpha = fexp2(m - mnew);
            l *= alpha;
            m = mnew;
#pragma unroll
            for (int r = 0; r < 16; ++r) {
                const int qr = (r & 3) + 8 * (r >> 2) + 4 * hi;
                const float ar = __shfl(alpha, qr);
                acc0[r] *= ar;
                acc1[r] *= ar;
            }
        }

        f32x16 e0, e1;
#pragma unroll
        for (int i = 0; i < 16; ++i) {
            e0[i] = fexp2(s0[i] - m);
            e1[i] = fexp2(s1[i] - m);
        }
        float ps = 0.f;
#pragma unroll
        for (int i = 0; i < 16; ++i) ps += e0[i] + e1[i];
        ps += __shfl_xor(ps, 32);
        l += ps;

        // ---- P -> PA frags in-register (cvt_pk + permlane32_swap) ----
        bf16x8 pa[4];
#pragma unroll
        for (int kt = 0; kt < 4; ++kt) {
            const f32x16& e = (kt & 2) ? e1 : e0;  // kvt = kt>>1
            const int sx = 8 * (kt & 1);
            unsigned wA = pk_bf16(e[sx + 0], e[sx + 1]);
            unsigned wB = pk_bf16(e[sx + 2], e[sx + 3]);
            unsigned wC = pk_bf16(e[sx + 4], e[sx + 5]);
            unsigned wD = pk_bf16(e[sx + 6], e[sx + 7]);
            asm("v_permlane32_swap_b32 %0, %1" : "+v"(wA), "+v"(wC));
            asm("v_permlane32_swap_b32 %0, %1" : "+v"(wB), "+v"(wD));
            u32x4v w;
            w[0] = wA; w[1] = wB; w[2] = wC; w[3] = wD;
            pa[kt] = __builtin_bit_cast(bf16x8, w);
        }

        // ---- O += P V: B-frag = VT[d][kv], lane: d=ln(+32), kv=kt*16+hi*8+b ----
        __builtin_amdgcn_s_setprio(1);
#pragma unroll
        for (int kt = 0; kt < 4; ++kt) {
            const int v0r = ln;
            bf16x8 vf0 = *(const bf16x8*)&vb[swz(v0r, v0r * 128 + kt * 32 + hi * 16)];
            acc0 = __builtin_amdgcn_mfma_f32_32x32x16_bf16(pa[kt], vf0, acc0, 0, 0, 0);
            const int v1r = 32 + ln;
            bf16x8 vf1 = *(const bf16x8*)&vb[swz(v1r, v1r * 128 + kt * 32 + hi * 16)];
            acc1 = __builtin_amdgcn_mfma_f32_32x32x16_bf16(pa[kt], vf1, acc1, 0, 0, 0);
        }
        __builtin_amdgcn_s_setprio(0);

#if !HAVE_GLLDS
        if (it + 1 < NTILE) {
            const int nxt = cur ^ 1;
            *(bf16x8*)&kbuf[nxt][t * 16] = n0;
            *(bf16x8*)&kbuf[nxt][4096 + t * 16] = n1;
            *(bf16x8*)&vbuf[nxt][t * 16] = n2;
            *(bf16x8*)&vbuf[nxt][4096 + t * 16] = n3;
        }
#endif
        __syncthreads();
    }

    // ---- epilogue: normalize and store f32 ----
    const float invl = 1.f / l;
#pragma unroll
    for (int r = 0; r < 16; ++r) {
        const int qr = (r & 3) + 8 * (r >> 2) + 4 * hi;
        const float il = __shfl(invl, qr);
        float* dst = Op + (size_t)(qbase + qr) * HD + ln;
        dst[0]  = acc0[r] * il;
        dst[32] = acc1[r] * il;
    }
}

// ---------------- fallback (R1-style kernel, no workspace needed) ----------------
__global__ __launch_bounds__(256, 2)
void attn_fwd_kernel(const float* __restrict__ x, float* __restrict__ out) {
    __shared__ __align__(16) char k_lds[KVB * HD * 2];
    __shared__ __align__(16) char vt_lds[HD * KVB * 2];
    __shared__ __align__(16) char p_lds2[4][2][16 * KVB * 2];

    const int bh = blockIdx.y;
    const int q0 = blockIdx.x * 128;
    const float* __restrict__ X = x + (size_t)bh * SEQ * HD;
    float* __restrict__ Op = out + (size_t)bh * SEQ * HD;

    const int t = threadIdx.x;
    const int wave = t >> 6;
    const int lane = t & 63;
    const int lgrp = lane >> 4;
    const int lid = lane & 15;

    bf16x8 qf[2][2];
#pragma unroll
    for (int rt = 0; rt < 2; ++rt) {
        const int row = q0 + wave * 32 + rt * 16 + lid;
#pragma unroll
        for (int kc = 0; kc < 2; ++kc) {
            const float* src = X + (size_t)row * HD + kc * 32 + lgrp * 8;
            float4 a = *(const float4*)src;
            float4 b = *(const float4*)(src + 4);
            bf16x8 f;
            f[0] = (__bf16)a.x; f[1] = (__bf16)a.y; f[2] = (__bf16)a.z; f[3] = (__bf16)a.w;
            f[4] = (__bf16)b.x; f[5] = (__bf16)b.y; f[6] = (__bf16)b.z; f[7] = (__bf16)b.w;
            qf[rt][kc] = f;
        }
    }

    f32x4 acc[2][4];
    float m[2][4], l[2][4];
#pragma unroll
    for (int rt = 0; rt < 2; ++rt)
#pragma unroll
        for (int i = 0; i < 4; ++i) {
            acc[rt][i][0] = 0.f; acc[rt][i][1] = 0.f;
            acc[rt][i][2] = 0.f; acc[rt][i][3] = 0.f;
            m[rt][i] = -1e30f;
            l[rt][i] = 0.f;
        }

    const int srow = t >> 2;
    const int scq = (t & 3) * 16;

    for (int kv0 = 0; kv0 < SEQ; kv0 += KVB) {
        {
            const float* src = X + (size_t)(kv0 + srow) * HD + scq;
            float4 a = *(const float4*)(src);
            float4 b = *(const float4*)(src + 4);
            float4 c = *(const float4*)(src + 8);
            float4 d = *(const float4*)(src + 12);
            bf16x8 f0, f1;
            f0[0] = (__bf16)a.x; f0[1] = (__bf16)a.y; f0[2] = (__bf16)a.z; f0[3] = (__bf16)a.w;
            f0[4] = (__bf16)b.x; f0[5] = (__bf16)b.y; f0[6] = (__bf16)b.z; f0[7] = (__bf16)b.w;
            f1[0] = (__bf16)c.x; f1[1] = (__bf16)c.y; f1[2] = (__bf16)c.z; f1[3] = (__bf16)c.w;
            f1[4] = (__bf16)d.x; f1[5] = (__bf16)d.y; f1[6] = (__bf16)d.z; f1[7] = (__bf16)d.w;
            *(bf16x8*)&k_lds[swz(srow, srow * 128 + scq * 2)] = f0;
            *(bf16x8*)&k_lds[swz(srow, srow * 128 + scq * 2 + 16)] = f1;
        }
        {
            bf16x8 g0, g1;
#pragma unroll
            for (int j = 0; j < 8; ++j)
                g0[j] = (__bf16)X[(size_t)(kv0 + scq + j) * HD + srow];
#pragma unroll
            for (int j = 0; j < 8; ++j)
                g1[j] = (__bf16)X[(size_t)(kv0 + scq + 8 + j) * HD + srow];
            *(bf16x8*)&vt_lds[swz(srow, srow * 128 + scq * 2)] = g0;
            *(bf16x8*)&vt_lds[swz(srow, srow * 128 + scq * 2 + 16)] = g1;
        }
        __syncthreads();

#pragma unroll
        for (int rt = 0; rt < 2; ++rt) {
            f32x4 s[4];
#pragma unroll
            for (int kt = 0; kt < 4; ++kt) {
                f32x4 z = {0.f, 0.f, 0.f, 0.f};
#pragma unroll
                for (int kc = 0; kc < 2; ++kc) {
                    const int krow = kt * 16 + lid;
                    bf16x8 kfr = *(const bf16x8*)&k_lds[swz(krow, krow * 128 + (kc * 32 + lgrp * 8) * 2)];
                    z = __builtin_amdgcn_mfma_f32_16x16x32_bf16(qf[rt][kc], kfr, z, 0, 0, 0);
                }
                s[kt] = z;
            }

            char* pl = p_lds2[wave][rt];
#pragma unroll
            for (int r = 0; r < 4; ++r) {
                float mxv = fmaxf(fmaxf(s[0][r], s[1][r]), fmaxf(s[2][r], s[3][r]));
                mxv = fmaxf(mxv, __shfl_xor(mxv, 1));
                mxv = fmaxf(mxv, __shfl_xor(mxv, 2));
                mxv = fmaxf(mxv, __shfl_xor(mxv, 4));
                mxv = fmaxf(mxv, __shfl_xor(mxv, 8));
                const float mold = m[rt][r];
                const float mnew = fmaxf(mold, mxv);
                const float alpha = __expf(mold - mnew);
                const int prow = lgrp * 4 + r;
                float psum = 0.f;
#pragma unroll
                for (int kt = 0; kt < 4; ++kt) {
                    float p = __expf(s[kt][r] - mnew);
                    psum += p;
                    *(__bf16*)&pl[swz(prow, prow * 128 + (kt * 16 + lid) * 2)] = (__bf16)p;
                }
                psum += __shfl_xor(psum, 1);
                psum += __shfl_xor(psum, 2);
                psum += __shfl_xor(psum, 4);
                psum += __shfl_xor(psum, 8);
                l[rt][r] = l[rt][r] * alpha + psum;
                m[rt][r] = mnew;
#pragma unroll
                for (int ct = 0; ct < 4; ++ct)
                    acc[rt][ct][r] *= alpha;
            }

#pragma unroll
            for (int kc = 0; kc < 2; ++kc) {
                bf16x8 pfr = *(const bf16x8*)&pl[swz(lid, lid * 128 + (kc * 32 + lgrp * 8) * 2)];
#pragma unroll
                for (int ct = 0; ct < 4; ++ct) {
                    const int vrow = ct * 16 + lid;
                    bf16x8 vf = *(const bf16x8*)&vt_lds[swz(vrow, vrow * 128 + (kc * 32 + lgrp * 8) * 2)];
                    acc[rt][ct] = __builtin_amdgcn_mfma_f32_16x16x32_bf16(pfr, vf, acc[rt][ct], 0, 0, 0);
                }
            }
        }
        __syncthreads();
    }

#pragma unroll
    for (int rt = 0; rt < 2; ++rt)
#pragma unroll
        for (int r = 0; r < 4; ++r) {
            const float inv = 1.f / l[rt][r];
            const int row = q0 + wave * 32 + rt * 16 + lgrp * 4 + r;
            float* dst = Op + (size_t)row * HD + lid;
#pragma unroll
            for (int ct = 0; ct < 4; ++ct)
                dst[ct * 16] = acc[rt][ct][r] * inv;
        }
}

extern "C" void kernel_launch(void* const* d_in, const int* in_sizes, int n_in,
                              void* d_out, int out_size, void* d_ws, size_t ws_size,
                              hipStream_t stream) {
    const float* x = (const float*)d_in[0];
    float* out = (float*)d_out;
    if (ws_size >= WS_NEEDED) {
        char* ws = (char*)d_ws;
        dim3 pgrid(NTILE, NBH);
        hipLaunchKernelGGL(prep_kernel, pgrid, dim3(256), 0, stream, x, ws);
        hipLaunchKernelGGL(attn4_kernel, dim3((SEQ / QPB) * NBH), dim3(256), 0, stream,
                           x, ws, out);
    } else {
        dim3 grid(SEQ / 128, NBH);
        hipLaunchKernelGGL(attn_fwd_kernel, grid, dim3(256), 0, stream, x, out);
    }
}